// Round 9
// baseline (225.090 us; speedup 1.0000x reference)
//
#include <hip/hip_runtime.h>
#include <math.h>

static constexpr float SCALE_F = (float)(2.0 * 28.0 * 0.32178);

// order-preserving float<->uint bijection for atomic max on floats
__device__ __forceinline__ unsigned mapf(float f){
    unsigned u = __float_as_uint(f);
    return (u & 0x80000000u) ? ~u : (u | 0x80000000u);
}
__device__ __forceinline__ float unmapf(unsigned m){
    unsigned u = (m & 0x80000000u) ? (m ^ 0x80000000u) : ~m;
    return __uint_as_float(u);
}
__device__ __forceinline__ float eluf(float x){ return x > 0.f ? x : expm1f(x); }

// Wave-local LDS visibility: lockstep wave + drain LDS queue. Used ONLY in the
// variable-trip gather phase (wave-private data); uniform phases use __syncthreads.
__device__ __forceinline__ void wave_sync(){
    __builtin_amdgcn_wave_barrier();
    asm volatile("s_waitcnt lgkmcnt(0)" ::: "memory");
    __builtin_amdgcn_wave_barrier();
}

// prep: init max-regions, zero sum-regions, pack {pos,x} float4, build 3 rowptrs. 1 dispatch.
__global__ void prep_kernel(const float* __restrict__ x, const float* __restrict__ pos, int N,
    const int* __restrict__ ei1, int E1, const int* __restrict__ ei2, int E2, int C1,
    const int* __restrict__ ei3, int E3, int C2,
    int* __restrict__ rp1, int* __restrict__ rp2, int* __restrict__ rp3,
    unsigned* __restrict__ hmax, int nmax, float* __restrict__ zreg, int nz,
    float4* __restrict__ xp1)
{
    int i0 = blockIdx.x*blockDim.x + threadIdx.x, gs = gridDim.x*blockDim.x;
    for (int i = i0; i < nmax; i += gs) hmax[i] = 0x007FFFFFu;  // mapf(-inf)
    for (int i = i0; i < nz;   i += gs) zreg[i] = 0.f;
    for (int i = i0; i < N;    i += gs) xp1[i] = make_float4(pos[2*i], pos[2*i+1], x[i], 0.f);
    int nrp = N + C1 + C2 + 3;
    for (int i = i0; i < nrp; i += gs){
        const int* rows; int E, n; int* rp;
        if (i <= N)            { rows = ei1; E = E1; n = i;            rp = rp1 + n; }
        else if (i <= N+1+C1)  { rows = ei2; E = E2; n = i - (N+1);    rp = rp2 + n; }
        else                   { rows = ei3; E = E3; n = i - (N+C1+2); rp = rp3 + n; }
        int lo = 0, hi = E;
        while (lo < hi){ int m = (lo+hi) >> 1; if (rows[m] < n) lo = m+1; else hi = m; }
        *rp = lo;
    }
}

// Layer 1: I=1, O=32. QUARTER-WAVE (16 lanes) per node; 16 nodes per 256-block. No barriers.
__global__ __launch_bounds__(256) void l1_kernel(const float4* __restrict__ xp1,
    const int* __restrict__ ei1, int E1, const int* __restrict__ rp1, const int* __restrict__ cl1,
    const float* __restrict__ g1, const float* __restrict__ mu1, const float* __restrict__ sg1,
    const float* __restrict__ rt1, const float* __restrict__ b1,
    unsigned* __restrict__ h2m, float4* __restrict__ pos2s4, int N)
{
    int t = threadIdx.x;
    int lane = t & 63, wv = t >> 6;
    int q = lane >> 4, il = lane & 15;
    int n = (blockIdx.x*4 + wv)*4 + q;
    if (n >= N) return;
    const int* cols = ei1 + E1;
    float mx[9], my[9], ivx[9], ivy[9];
    #pragma unroll
    for (int k = 0; k < 9; k++){
        mx[k] = mu1[2*k]; my[k] = mu1[2*k+1];
        float sx = sg1[2*k], sy = sg1[2*k+1];
        ivx[k] = 1.f/(sx*sx); ivy[k] = 1.f/(sy*sy);
    }
    float4 me = xp1[n];
    float px = me.x, py = me.y, xn = me.z;
    int e0 = rp1[n], e1 = rp1[n+1];
    float s[9] = {0.f,0.f,0.f,0.f,0.f,0.f,0.f,0.f,0.f};
    for (int e = e0 + il; e < e1; e += 16){
        int j = cols[e];
        float4 pj = xp1[j];
        float ux = (px - pj.x)/SCALE_F + 0.5f;
        float uy = (py - pj.y)/SCALE_F + 0.5f;
        #pragma unroll
        for (int k = 0; k < 9; k++){
            float dx = ux - mx[k], dy = uy - my[k];
            s[k] += pj.z * expf(-0.5f*(dx*dx*ivx[k] + dy*dy*ivy[k]));
        }
    }
    #pragma unroll
    for (int off = 8; off > 0; off >>= 1){
        #pragma unroll
        for (int k = 0; k < 9; k++) s[k] += __shfl_xor(s[k], off, 16);
    }
    float inv = 1.f / (float)max(e1 - e0, 1);
    int c = cl1[n];
    #pragma unroll
    for (int oo = 0; oo < 2; oo++){
        int o = il + oo*16;
        float acc = 0.f;
        #pragma unroll
        for (int k = 0; k < 9; k++) acc += g1[k*32+o] * s[k];
        float v = acc*inv + xn*rt1[o] + b1[o];
        atomicMax(&h2m[(size_t)c*32 + o], mapf(eluf(v)));
    }
    if (il == 0){
        atomicAdd(&pos2s4[c].x, px);
        atomicAdd(&pos2s4[c].y, py);
        atomicAdd(&pos2s4[c].z, 1.f);
    }
}

// Layer 2: I=32, O=64. Wave-per-node gather (unroll-4 batched loads), 8 waves/block,
// then LOCKSTEP LDS-staged tiled contraction (g2 in 32x64 tiles shared by all 8 waves).
__global__ __launch_bounds__(512) void l2_kernel(const unsigned* __restrict__ h2m,
    const float4* __restrict__ pos2s4,
    const int* __restrict__ ei2, int E2, const int* __restrict__ rp2, const int* __restrict__ cl2,
    const float* __restrict__ g2, const float* __restrict__ mu2, const float* __restrict__ sg2,
    const float* __restrict__ rt2, const float* __restrict__ b2,
    unsigned* __restrict__ h3m, float4* __restrict__ pos3s4, int C1)
{
    __shared__ float wbuf[8][576];   // per-wave: Wc[64][9] during gather, then Ssum[288]
    __shared__ int   jcs[8][64];
    __shared__ float xns[8][32];
    __shared__ float gt[32*64];      // staged g2/rt2 tile (8 KB)
    int t = threadIdx.x, l = t & 63, w = t >> 6;
    int n0 = blockIdx.x*8 + w;
    int n = min(n0, C1-1);
    bool active = (n0 < C1);
    const int* cols = ei2 + E2;
    float mx[9], my[9], ivx[9], ivy[9];
    #pragma unroll
    for (int k = 0; k < 9; k++){
        mx[k] = mu2[2*k]; my[k] = mu2[2*k+1];
        float sx = sg2[2*k], sy = sg2[2*k+1];
        ivx[k] = 1.f/(sx*sx); ivy[k] = 1.f/(sy*sy);
    }
    if (l < 32) xns[w][l] = unmapf(h2m[(size_t)n*32 + l]);
    float4 pm = pos2s4[n];
    float cn = fmaxf(pm.z, 1.f);
    float px = pm.x/cn, py = pm.y/cn;
    int e0 = rp2[n], e1 = rp2[n+1], deg = e1 - e0;
    int i = l & 31, half = l >> 5;
    float sacc[9] = {0.f,0.f,0.f,0.f,0.f,0.f,0.f,0.f,0.f};
    for (int base = e0; base < e1; base += 64){
        int ne = min(64, e1 - base);
        if (l < ne){
            int j = cols[base + l];
            jcs[w][l] = j;
            float4 pj = pos2s4[j];
            float cj = fmaxf(pj.z, 1.f);
            float ux = (px - pj.x/cj)/SCALE_F + 0.5f;
            float uy = (py - pj.y/cj)/SCALE_F + 0.5f;
            #pragma unroll
            for (int k = 0; k < 9; k++){
                float dx = ux - mx[k], dy = uy - my[k];
                wbuf[w][l*9+k] = expf(-0.5f*(dx*dx*ivx[k] + dy*dy*ivy[k]));
            }
        }
        wave_sync();
        // unroll-by-4: batch 4 independent row loads before their FMAs (jj order kept)
        int jj = half;
        for (; jj + 6 < ne; jj += 8){
            int j0 = jcs[w][jj],   j1 = jcs[w][jj+2];
            int j2 = jcs[w][jj+4], j3 = jcs[w][jj+6];
            float x0 = unmapf(h2m[(size_t)j0*32 + i]);
            float x1 = unmapf(h2m[(size_t)j1*32 + i]);
            float x2 = unmapf(h2m[(size_t)j2*32 + i]);
            float x3 = unmapf(h2m[(size_t)j3*32 + i]);
            #pragma unroll
            for (int k = 0; k < 9; k++) sacc[k] += x0 * wbuf[w][(jj  )*9+k];
            #pragma unroll
            for (int k = 0; k < 9; k++) sacc[k] += x1 * wbuf[w][(jj+2)*9+k];
            #pragma unroll
            for (int k = 0; k < 9; k++) sacc[k] += x2 * wbuf[w][(jj+4)*9+k];
            #pragma unroll
            for (int k = 0; k < 9; k++) sacc[k] += x3 * wbuf[w][(jj+6)*9+k];
        }
        for (; jj < ne; jj += 2){
            int j = jcs[w][jj];
            float xji = unmapf(h2m[(size_t)j*32 + i]);
            #pragma unroll
            for (int k = 0; k < 9; k++) sacc[k] += xji * wbuf[w][jj*9+k];
        }
        wave_sync();
    }
    #pragma unroll
    for (int k = 0; k < 9; k++) sacc[k] += __shfl_xor(sacc[k], 32, 64);
    if (l < 32){
        #pragma unroll
        for (int k = 0; k < 9; k++) wbuf[w][l*9+k] = sacc[k];  // Ssum[0..287] overwrites Wc
    }
    // ---- lockstep tiled contraction: 9 tiles of g2 (32x64) + 1 root tile (rt2, 32x64)
    float acc = 0.f, racc = 0.f;
    for (int tile = 0; tile < 10; tile++){
        __syncthreads();
        const float4* src = (tile < 9) ? (const float4*)(g2 + tile*2048) : (const float4*)rt2;
        ((float4*)gt)[t] = src[t];   // 512 threads x 1 float4 = 2048 floats
        __syncthreads();
        if (tile < 9){
            #pragma unroll 8
            for (int ii = 0; ii < 32; ii++) acc += gt[ii*64 + l] * wbuf[w][tile*32 + ii];
        } else {
            #pragma unroll 8
            for (int ii = 0; ii < 32; ii++) racc += gt[ii*64 + l] * xns[w][ii];
        }
    }
    float inv = 1.f / (float)max(deg, 1);
    float h = eluf(acc*inv + racc + b2[l]);
    if (active){
        int c = cl2[n];
        atomicMax(&h3m[(size_t)c*64 + l], mapf(h));
        if (l == 0){
            atomicAdd(&pos3s4[c].x, px);
            atomicAdd(&pos3s4[c].y, py);
            atomicAdd(&pos3s4[c].z, 1.f);
        }
    }
}

// Layer 3: I=64, O=64. Wave-per-node gather (unroll-4 batched loads), 8 waves/block,
// then LOCKSTEP LDS-staged tiled contraction (g3 in 64x64 tiles shared by all 8 waves).
__global__ __launch_bounds__(512) void l3_kernel(const unsigned* __restrict__ h3m,
    const float4* __restrict__ pos3s4,
    const int* __restrict__ ei3, int E3, const int* __restrict__ rp3,
    const float* __restrict__ g3, const float* __restrict__ mu3, const float* __restrict__ sg3,
    const float* __restrict__ rt3, const float* __restrict__ b3,
    float* __restrict__ gpart, int C2)
{
    __shared__ float wbuf[8][576];   // per-wave: Wc[64][9] during gather, then Ssum[576]
    __shared__ int   jcs[8][64];
    __shared__ float xns[8][64];
    __shared__ float gt[64*64];      // staged g3/rt3 tile (16 KB)
    int t = threadIdx.x, l = t & 63, w = t >> 6;
    int n0 = blockIdx.x*8 + w;
    int n = min(n0, C2-1);
    bool active = (n0 < C2);
    const int* cols = ei3 + E3;
    float mx[9], my[9], ivx[9], ivy[9];
    #pragma unroll
    for (int k = 0; k < 9; k++){
        mx[k] = mu3[2*k]; my[k] = mu3[2*k+1];
        float sx = sg3[2*k], sy = sg3[2*k+1];
        ivx[k] = 1.f/(sx*sx); ivy[k] = 1.f/(sy*sy);
    }
    xns[w][l] = unmapf(h3m[(size_t)n*64 + l]);
    float4 pm = pos3s4[n];
    float cn = fmaxf(pm.z, 1.f);
    float px = pm.x/cn, py = pm.y/cn;
    int e0 = rp3[n], e1 = rp3[n+1], deg = e1 - e0;
    float sacc[9] = {0.f,0.f,0.f,0.f,0.f,0.f,0.f,0.f,0.f};
    for (int base = e0; base < e1; base += 64){
        int ne = min(64, e1 - base);
        if (l < ne){
            int j = cols[base + l];
            jcs[w][l] = j;
            float4 pj = pos3s4[j];
            float cj = fmaxf(pj.z, 1.f);
            float ux = (px - pj.x/cj)/SCALE_F + 0.5f;
            float uy = (py - pj.y/cj)/SCALE_F + 0.5f;
            #pragma unroll
            for (int k = 0; k < 9; k++){
                float dx = ux - mx[k], dy = uy - my[k];
                wbuf[w][l*9+k] = expf(-0.5f*(dx*dx*ivx[k] + dy*dy*ivy[k]));
            }
        }
        wave_sync();
        // unroll-by-4: batch 4 independent row loads before their FMAs (jj order kept)
        int jj = 0;
        for (; jj + 3 < ne; jj += 4){
            int j0 = jcs[w][jj],   j1 = jcs[w][jj+1];
            int j2 = jcs[w][jj+2], j3 = jcs[w][jj+3];
            float x0 = unmapf(h3m[(size_t)j0*64 + l]);
            float x1 = unmapf(h3m[(size_t)j1*64 + l]);
            float x2 = unmapf(h3m[(size_t)j2*64 + l]);
            float x3 = unmapf(h3m[(size_t)j3*64 + l]);
            #pragma unroll
            for (int k = 0; k < 9; k++) sacc[k] += x0 * wbuf[w][(jj  )*9+k];
            #pragma unroll
            for (int k = 0; k < 9; k++) sacc[k] += x1 * wbuf[w][(jj+1)*9+k];
            #pragma unroll
            for (int k = 0; k < 9; k++) sacc[k] += x2 * wbuf[w][(jj+2)*9+k];
            #pragma unroll
            for (int k = 0; k < 9; k++) sacc[k] += x3 * wbuf[w][(jj+3)*9+k];
        }
        for (; jj < ne; jj++){
            int j = jcs[w][jj];
            float xji = unmapf(h3m[(size_t)j*64 + l]);
            #pragma unroll
            for (int k = 0; k < 9; k++) sacc[k] += xji * wbuf[w][jj*9+k];
        }
        wave_sync();
    }
    #pragma unroll
    for (int k = 0; k < 9; k++) wbuf[w][l*9+k] = sacc[k];  // Ssum[i*9+k], i=l
    // ---- lockstep tiled contraction: 9 tiles of g3 (64x64) + 1 root tile (rt3, 64x64)
    float acc = 0.f, racc = 0.f;
    for (int tile = 0; tile < 10; tile++){
        __syncthreads();
        const float4* src = (tile < 9) ? (const float4*)(g3 + tile*4096) : (const float4*)rt3;
        float4* dst = (float4*)gt;
        #pragma unroll
        for (int r = 0; r < 2; r++) dst[t + 512*r] = src[t + 512*r];  // 4096 floats
        __syncthreads();
        if (tile < 9){
            #pragma unroll 8
            for (int ii = 0; ii < 64; ii++) acc += gt[ii*64 + l] * wbuf[w][tile*64 + ii];
        } else {
            #pragma unroll 8
            for (int ii = 0; ii < 64; ii++) racc += gt[ii*64 + l] * xns[w][ii];
        }
    }
    float inv = 1.f / (float)max(deg, 1);
    float h = eluf(acc*inv + racc + b3[l]);
    if (active) atomicAdd(&gpart[(size_t)(n & 63)*64 + l], h);
}

__global__ void final_kernel(const float* __restrict__ gpart, const float* __restrict__ fw,
                             const float* __restrict__ fb, float* __restrict__ out, int C2){
    __shared__ float gs[64];
    __shared__ float red[2*64];
    int t = threadIdx.x;           // 128 threads
    int o = t & 63, h = t >> 6;
    float a = 0.f;
    for (int p = h*32; p < h*32 + 32; p++) a += gpart[p*64 + o];
    red[h*64 + o] = a;
    __syncthreads();
    if (t < 64) gs[t] = (red[t] + red[64+t]) / (float)C2;
    __syncthreads();
    float acc = fb[t];
    for (int o2 = 0; o2 < 64; o2++) acc += gs[o2] * fw[o2*128 + t];
    out[t] = acc;
}

extern "C" void kernel_launch(void* const* d_in, const int* in_sizes, int n_in,
                              void* d_out, int out_size, void* d_ws, size_t ws_size,
                              hipStream_t stream)
{
    const float* x    = (const float*)d_in[0];
    const float* pos  = (const float*)d_in[1];
    const int*   ei1  = (const int*)d_in[2];
    const int*   cl1  = (const int*)d_in[3];
    const int*   ei2  = (const int*)d_in[4];
    const int*   cl2  = (const int*)d_in[5];
    const int*   ei3  = (const int*)d_in[6];
    const float* g1   = (const float*)d_in[8];
    const float* mu1  = (const float*)d_in[9];
    const float* sg1  = (const float*)d_in[10];
    const float* rt1  = (const float*)d_in[11];
    const float* b1   = (const float*)d_in[12];
    const float* g2   = (const float*)d_in[13];
    const float* mu2  = (const float*)d_in[14];
    const float* sg2  = (const float*)d_in[15];
    const float* rt2  = (const float*)d_in[16];
    const float* b2   = (const float*)d_in[17];
    const float* g3   = (const float*)d_in[18];
    const float* mu3  = (const float*)d_in[19];
    const float* sg3  = (const float*)d_in[20];
    const float* rt3  = (const float*)d_in[21];
    const float* b3   = (const float*)d_in[22];
    const float* fw   = (const float*)d_in[23];
    const float* fb   = (const float*)d_in[24];
    float* out = (float*)d_out;

    const int N  = in_sizes[0];
    const int E1 = in_sizes[2] / 2;
    const int C1 = in_sizes[5];
    const int E2 = in_sizes[4] / 2;
    const int C2 = in_sizes[7];
    const int E3 = in_sizes[6] / 2;

    // workspace layout (float4 arrays first for 16B alignment; counts are multiples of 4)
    float* w = (float*)d_ws;
    size_t off = 0;
    float4* xp1    = (float4*)(w + off); off += (size_t)4*N;
    float4* pos2s4 = (float4*)(w + off); off += (size_t)4*C1;   // zero-region start
    float4* pos3s4 = (float4*)(w + off); off += (size_t)4*C2;
    float*  gpart  = w + off;            off += 64*64;
    int* rp1 = (int*)(w + off); off += (size_t)N + 1;
    int* rp2 = (int*)(w + off); off += (size_t)C1 + 1;
    int* rp3 = (int*)(w + off); off += (size_t)C2 + 1;
    unsigned* h2m = (unsigned*)(w + off); off += (size_t)C1 * 32;  // max-region (contiguous)
    unsigned* h3m = (unsigned*)(w + off); off += (size_t)C2 * 64;

    const int nmax = C1*32 + C2*64;
    const int nz   = 4*C1 + 4*C2 + 64*64;
    prep_kernel<<<dim3(1024), dim3(256), 0, stream>>>(x, pos, N,
        ei1, E1, ei2, E2, C1, ei3, E3, C2,
        rp1, rp2, rp3, h2m, nmax, (float*)pos2s4, nz, xp1);

    l1_kernel<<<dim3((N + 15)/16), dim3(256), 0, stream>>>(xp1, ei1, E1, rp1, cl1,
        g1, mu1, sg1, rt1, b1, h2m, pos2s4, N);
    l2_kernel<<<dim3((C1 + 7)/8), dim3(512), 0, stream>>>(h2m, pos2s4, ei2, E2, rp2, cl2,
        g2, mu2, sg2, rt2, b2, h3m, pos3s4, C1);
    l3_kernel<<<dim3((C2 + 7)/8), dim3(512), 0, stream>>>(h3m, pos3s4, ei3, E3, rp3,
        g3, mu3, sg3, rt3, b3, gpart, C2);
    final_kernel<<<dim3(1), dim3(128), 0, stream>>>(gpart, fw, fb, out, C2);
}